// Round 10
// baseline (48.142 us; speedup 1.0000x reference)
//
#include <hip/hip_runtime.h>
#include <math.h>

#define D      2048
#define KSEL   256
#define NT     256          // threads per block; NT*8 == D
#define NBINS  512          // bins of width 1/64 over |z| in [0,8)
#define ROWS   4            // rows per block, processed serially

typedef float f4 __attribute__((ext_vector_type(4)));
typedef int   i4 __attribute__((ext_vector_type(4)));

// tanh-form GELU: x * sigmoid(1.5957691*x + 0.0713548*x^3)
__device__ __forceinline__ float fast_gelu(float x) {
    float x2 = x * x;
    float t  = fmaf(x2, -0.0713548162f, -1.5957691216f);
    float e  = __expf(x * t);
    return x * __builtin_amdgcn_rcpf(1.0f + e);
}

// ---- DPP cross-lane (VALU pipe, no LDS) ----
template<int CTRL, int RMASK>
__device__ __forceinline__ float dpp_mov_f(float v) {
    int r = __builtin_amdgcn_update_dpp(0, __builtin_bit_cast(int, v),
                                        CTRL, RMASK, 0xf, true);
    return __builtin_bit_cast(float, r);
}
template<int CTRL, int RMASK>
__device__ __forceinline__ int dpp_mov_i(int v) {
    return __builtin_amdgcn_update_dpp(0, v, CTRL, RMASK, 0xf, true);
}
// inclusive prefix-sum across 64 lanes; lane 63 ends with the wave total
__device__ __forceinline__ float wave_scan_f(float x) {
    x += dpp_mov_f<0x111, 0xf>(x);   // row_shr:1
    x += dpp_mov_f<0x112, 0xf>(x);   // row_shr:2
    x += dpp_mov_f<0x114, 0xf>(x);   // row_shr:4
    x += dpp_mov_f<0x118, 0xf>(x);   // row_shr:8
    x += dpp_mov_f<0x142, 0xa>(x);   // row_bcast:15 -> rows 1,3
    x += dpp_mov_f<0x143, 0xc>(x);   // row_bcast:31 -> rows 2,3
    return x;
}
__device__ __forceinline__ int wave_scan_i(int x) {
    x += dpp_mov_i<0x111, 0xf>(x);
    x += dpp_mov_i<0x112, 0xf>(x);
    x += dpp_mov_i<0x114, 0xf>(x);
    x += dpp_mov_i<0x118, 0xf>(x);
    x += dpp_mov_i<0x142, 0xa>(x);
    x += dpp_mov_i<0x143, 0xc>(x);
    return x;
}
__device__ __forceinline__ int wave_or_i(int x) {
    x |= dpp_mov_i<0x111, 0xf>(x);
    x |= dpp_mov_i<0x112, 0xf>(x);
    x |= dpp_mov_i<0x114, 0xf>(x);
    x |= dpp_mov_i<0x118, 0xf>(x);
    x |= dpp_mov_i<0x142, 0xa>(x);
    x |= dpp_mov_i<0x143, 0xc>(x);
    return x;
}

// Everything fused: no prep kernel, no workspace.
__global__ __launch_bounds__(NT) void row_kernel(
    const float* __restrict__ x,
    const float* __restrict__ ema_mean,
    const float* __restrict__ ema_sq,
    const float* __restrict__ ema_out,
    const float* __restrict__ p_log_tau,
    const float* __restrict__ p_log_sigma,
    const float* __restrict__ p_log_w,
    float* __restrict__ out)
{
    __shared__ int   hist[2][NBINS];  // double-buffered, REVERSED index
    __shared__ float ssred[4];
    __shared__ float red[4][3];

    const int t    = threadIdx.x;
    const int wave = t >> 6;
    const int lane = t & 63;

    // scalar gate params (uniform; cheap redundant compute per block)
    const float tau   = __expf(p_log_tau[0]);
    const float sigma = __logf(1.0f + __expf(p_log_sigma[0])) + 0.01f;
    const float w     = __logf(1.0f + __expf(p_log_w[0]));

    // ---- inline "prep": per-thread channel constants ----
    f4 m0 = ((const f4*)ema_mean)[t];
    f4 m1 = ((const f4*)ema_mean)[t + NT];
    f4 q0 = ((const f4*)ema_sq)[t];
    f4 q1 = ((const f4*)ema_sq)[t + NT];
    f4 e0 = ((const f4*)ema_out)[t];
    f4 e1 = ((const f4*)ema_out)[t + NT];

    const float mv[8] = {m0.x,m0.y,m0.z,m0.w, m1.x,m1.y,m1.z,m1.w};
    const float qv[8] = {q0.x,q0.y,q0.z,q0.w, q1.x,q1.y,q1.z,q1.w};
    const float ev[8] = {e0.x,e0.y,e0.z,e0.w, e1.x,e1.y,e1.z,e1.w};

    float a_[8], b_[8];
    float ss = 0.f;
#pragma unroll
    for (int j = 0; j < 8; ++j) {
        float v = fmaxf(fmaf(-mv[j], mv[j], qv[j]), 1e-6f);
        a_[j] = 64.0f * __builtin_amdgcn_rsqf(v);     // 64/std
        b_[j] = -mv[j] * a_[j];
        ss = fmaf(ev[j], ev[j], ss);
    }
    ss = wave_scan_f(ss);
    if (lane == 63) ssred[wave] = ss;

    const size_t row0 = (size_t)blockIdx.x * ROWS;
    f4 xa = ((const f4*)(x + row0 * D))[t];
    f4 xb = ((const f4*)(x + row0 * D))[t + NT];

    hist[0][t] = 0;  hist[0][t + NT] = 0;
    hist[1][t] = 0;  hist[1][t + NT] = 0;
    __syncthreads();                       // B0: zeros + ssred visible

    const float inv_nrm =
        1.0f / (sqrtf(ssred[0] + ssred[1] + ssred[2] + ssred[3]) + 1e-8f);
    float u_[8];
#pragma unroll
    for (int j = 0; j < 8; ++j) u_[j] = ev[j] * inv_nrm;

#pragma unroll
    for (int r = 0; r < ROWS; ++r) {
        const int p = r & 1;
        const float xv[8] = {xa.x,xa.y,xa.z,xa.w, xb.x,xb.y,xb.z,xb.w};

        float g[8], av[8];
        float dot = 0.f, nrm = 0.f;
#pragma unroll
        for (int j = 0; j < 8; ++j) {
            float gg = fast_gelu(xv[j]);
            g[j] = gg;
            av[j] = fabsf(fmaf(xv[j], a_[j], b_[j]));   // 64*|z|
            dot = fmaf(gg, u_[j], dot);
            nrm = fmaf(gg, gg, nrm);
        }

        // prefetch next row's x — latency hides under this row's epilogue
        if (r + 1 < ROWS) {
            const float* xn = x + (row0 + r + 1) * D;
            xa = ((const f4*)xn)[t];
            xb = ((const f4*)xn)[t + NT];
        }

        // early cross-lane reduce of dot/nrm (VALU; overlaps DS atomics)
        dot = wave_scan_f(dot);
        nrm = wave_scan_f(nrm);
        if (lane == 63) { red[wave][0] = dot; red[wave][1] = nrm; }

        // reversed-bin histogram into buffer p
#pragma unroll
        for (int j = 0; j < 8; ++j) {
            int bin = (int)av[j];
            bin = bin > NBINS - 1 ? NBINS - 1 : bin;
            atomicAdd(&hist[p][(NBINS - 1) - bin], 1);
        }
        __syncthreads();                   // B1: hist[p] + red[0,1] ready

        // ALL waves scan hist[p] (8 bins/lane); rezero other buffer
        int enc;
        {
            i4 va = *(const i4*)&hist[p][8 * lane];
            i4 vb = *(const i4*)&hist[p][8 * lane + 4];
            hist[p ^ 1][t] = 0;            // overlap: rezero other buffer
            hist[p ^ 1][t + NT] = 0;
            int c0 = va.x;
            int c1 = c0 + va.y;
            int c2 = c1 + va.z;
            int c3 = c2 + va.w;
            int c4 = c3 + vb.x;
            int c5 = c4 + vb.y;
            int c6 = c5 + vb.z;
            int c7 = c6 + vb.w;
            int incl = wave_scan_i(c7);
            int excl = incl - c7;
            const int pre[8] = {0, c0, c1, c2, c3, c4, c5, c6};
            const int cum[8] = {c0, c1, c2, c3, c4, c5, c6, c7};
            enc = 0;
#pragma unroll
            for (int k = 0; k < 8; ++k) {
                int s0 = excl + pre[k];
                int e0x = excl + cum[k];
                if (s0 < KSEL && e0x >= KSEL)
                    enc = ((NBINS - 1) - (8 * lane + k)) | ((KSEL - s0) << 16);
            }
            enc = wave_or_i(enc);
            enc = __builtin_amdgcn_readlane(enc, 63);   // wave-uniform
        }
        const int   bsel = enc & 0xffff;
        const int   krem = enc >> 16;
        const float hi  = (bsel == NBINS - 1) ? __builtin_inff() : (float)(bsel + 1);
        const float mid = (float)bsel + 0.5f;

        float s = 0.f;
#pragma unroll
        for (int j = 0; j < 8; ++j) {
            s += (av[j] >= hi) ? av[j] : 0.f;
        }
        s = wave_scan_f(s);
        if (lane == 63) red[wave][2] = s;
        __syncthreads();                   // B2: red[2] + scan reads done

        dot = red[0][0] + red[1][0] + red[2][0] + red[3][0];
        nrm = red[0][1] + red[1][1] + red[2][1] + red[3][1];
        s   = red[0][2] + red[1][2] + red[2][2] + red[3][2];

        // true topk_sum = (s + krem*mid)/64 ; mean = /KSEL
        const float topk_mean = (s + (float)krem * mid) * (1.0f / (64.0f * KSEL));
        const float cosv = dot * __builtin_amdgcn_rsqf(fmaxf(nrm, 1e-24f));
        const float yt = sigma * topk_mean;
        const float et = __expf(-2.0f * yt);
        const float th = (1.0f - et) * __builtin_amdgcn_rcpf(1.0f + et);  // tanh
        const float gate = __expf(-tau * cosv) * fmaf(w, th, 1.0f);

        f4 oa, ob;
        oa.x = g[0]*gate; oa.y = g[1]*gate; oa.z = g[2]*gate; oa.w = g[3]*gate;
        ob.x = g[4]*gate; ob.y = g[5]*gate; ob.z = g[6]*gate; ob.w = g[7]*gate;
        f4* outr = (f4*)(out + (row0 + r) * D);
        outr[t]      = oa;
        outr[t + NT] = ob;
    }
}

extern "C" void kernel_launch(void* const* d_in, const int* in_sizes, int n_in,
                              void* d_out, int out_size, void* d_ws, size_t ws_size,
                              hipStream_t stream) {
    (void)n_in; (void)out_size; (void)d_ws; (void)ws_size;
    const float* x         = (const float*)d_in[0];
    const float* ema_mean  = (const float*)d_in[1];
    const float* ema_sq    = (const float*)d_in[2];
    const float* ema_out   = (const float*)d_in[3];
    const float* log_tau   = (const float*)d_in[4];
    const float* log_sigma = (const float*)d_in[5];
    const float* log_w     = (const float*)d_in[6];
    float* out = (float*)d_out;

    const int rows = in_sizes[0] / D;   // B*T = 16384
    row_kernel<<<rows / ROWS, NT, 0, stream>>>(x, ema_mean, ema_sq, ema_out,
                                               log_tau, log_sigma, log_w, out);
}

// Round 11
// 47.091 us; speedup vs baseline: 1.0223x; 1.0223x over previous
//
#include <hip/hip_runtime.h>
#include <math.h>

#define D      2048
#define KSEL   256
#define NT     256          // threads per block; NT*8 == D
#define NBINS  512          // bins of width 1/64 over |z| in [0,8)
#define ROWS   2            // rows per block; one hist buffer per row

typedef float f4 __attribute__((ext_vector_type(4)));
typedef int   i4 __attribute__((ext_vector_type(4)));

// tanh-form GELU: x * sigmoid(1.5957691*x + 0.0713548*x^3)
__device__ __forceinline__ float fast_gelu(float x) {
    float x2 = x * x;
    float t  = fmaf(x2, -0.0713548162f, -1.5957691216f);
    float e  = __expf(x * t);
    return x * __builtin_amdgcn_rcpf(1.0f + e);
}

// ---- DPP cross-lane (VALU pipe, no LDS) ----
template<int CTRL, int RMASK>
__device__ __forceinline__ float dpp_mov_f(float v) {
    int r = __builtin_amdgcn_update_dpp(0, __builtin_bit_cast(int, v),
                                        CTRL, RMASK, 0xf, true);
    return __builtin_bit_cast(float, r);
}
template<int CTRL, int RMASK>
__device__ __forceinline__ int dpp_mov_i(int v) {
    return __builtin_amdgcn_update_dpp(0, v, CTRL, RMASK, 0xf, true);
}
// inclusive prefix-sum across 64 lanes; lane 63 ends with the wave total
__device__ __forceinline__ float wave_scan_f(float x) {
    x += dpp_mov_f<0x111, 0xf>(x);   // row_shr:1
    x += dpp_mov_f<0x112, 0xf>(x);   // row_shr:2
    x += dpp_mov_f<0x114, 0xf>(x);   // row_shr:4
    x += dpp_mov_f<0x118, 0xf>(x);   // row_shr:8
    x += dpp_mov_f<0x142, 0xa>(x);   // row_bcast:15 -> rows 1,3
    x += dpp_mov_f<0x143, 0xc>(x);   // row_bcast:31 -> rows 2,3
    return x;
}
__device__ __forceinline__ int wave_scan_i(int x) {
    x += dpp_mov_i<0x111, 0xf>(x);
    x += dpp_mov_i<0x112, 0xf>(x);
    x += dpp_mov_i<0x114, 0xf>(x);
    x += dpp_mov_i<0x118, 0xf>(x);
    x += dpp_mov_i<0x142, 0xa>(x);
    x += dpp_mov_i<0x143, 0xc>(x);
    return x;
}
__device__ __forceinline__ float wave_bcast63_f(float x) {
    int r = __builtin_amdgcn_readlane(__builtin_bit_cast(int, x), 63);
    return __builtin_bit_cast(float, r);
}

// Fused, one barrier per row. No prep kernel, no workspace.
__global__ __launch_bounds__(NT) void row_kernel(
    const float* __restrict__ x,
    const float* __restrict__ ema_mean,
    const float* __restrict__ ema_sq,
    const float* __restrict__ ema_out,
    const float* __restrict__ p_log_tau,
    const float* __restrict__ p_log_sigma,
    const float* __restrict__ p_log_w,
    float* __restrict__ out)
{
    __shared__ int   hist[ROWS][NBINS];   // per-row buffer, REVERSED index
    __shared__ float ssred[4];
    __shared__ float red[ROWS][4][2];     // per-row dot/nrm partials

    const int t    = threadIdx.x;
    const int wave = t >> 6;
    const int lane = t & 63;

    // scalar gate params (uniform; cheap redundant compute per block)
    const float tau   = __expf(p_log_tau[0]);
    const float sigma = __logf(1.0f + __expf(p_log_sigma[0])) + 0.01f;
    const float w     = __logf(1.0f + __expf(p_log_w[0]));

    // ---- inline "prep": per-thread channel constants ----
    f4 m0 = ((const f4*)ema_mean)[t];
    f4 m1 = ((const f4*)ema_mean)[t + NT];
    f4 q0 = ((const f4*)ema_sq)[t];
    f4 q1 = ((const f4*)ema_sq)[t + NT];
    f4 e0 = ((const f4*)ema_out)[t];
    f4 e1 = ((const f4*)ema_out)[t + NT];

    const float mv[8] = {m0.x,m0.y,m0.z,m0.w, m1.x,m1.y,m1.z,m1.w};
    const float qv[8] = {q0.x,q0.y,q0.z,q0.w, q1.x,q1.y,q1.z,q1.w};
    const float ev[8] = {e0.x,e0.y,e0.z,e0.w, e1.x,e1.y,e1.z,e1.w};

    float a_[8], b_[8];
    float ss = 0.f;
#pragma unroll
    for (int j = 0; j < 8; ++j) {
        float v = fmaxf(fmaf(-mv[j], mv[j], qv[j]), 1e-6f);
        a_[j] = 64.0f * __builtin_amdgcn_rsqf(v);     // 64/std
        b_[j] = -mv[j] * a_[j];
        ss = fmaf(ev[j], ev[j], ss);
    }
    ss = wave_scan_f(ss);
    if (lane == 63) ssred[wave] = ss;

    const size_t row0 = (size_t)blockIdx.x * ROWS;
    f4 xa = ((const f4*)(x + row0 * D))[t];
    f4 xb = ((const f4*)(x + row0 * D))[t + NT];

    hist[0][t] = 0;  hist[0][t + NT] = 0;
    hist[1][t] = 0;  hist[1][t + NT] = 0;
    __syncthreads();                       // B0: zeros + ssred visible

    const float inv_nrm =
        1.0f / (sqrtf(ssred[0] + ssred[1] + ssred[2] + ssred[3]) + 1e-8f);
    float u_[8];
#pragma unroll
    for (int j = 0; j < 8; ++j) u_[j] = ev[j] * inv_nrm;

#pragma unroll
    for (int r = 0; r < ROWS; ++r) {
        const float xv[8] = {xa.x,xa.y,xa.z,xa.w, xb.x,xb.y,xb.z,xb.w};

        float g[8], av[8];
        float dot = 0.f, nrm = 0.f;
#pragma unroll
        for (int j = 0; j < 8; ++j) {
            float gg = fast_gelu(xv[j]);
            g[j] = gg;
            av[j] = fabsf(fmaf(xv[j], a_[j], b_[j]));   // 64*|z|
            dot = fmaf(gg, u_[j], dot);
            nrm = fmaf(gg, gg, nrm);
        }

        // prefetch next row's x
        if (r + 1 < ROWS) {
            const float* xn = x + (row0 + r + 1) * D;
            xa = ((const f4*)xn)[t];
            xb = ((const f4*)xn)[t + NT];
        }

        // cross-lane reduce dot/nrm on VALU; overlaps DS atomics below
        dot = wave_scan_f(dot);
        nrm = wave_scan_f(nrm);
        if (lane == 63) { red[r][wave][0] = dot; red[r][wave][1] = nrm; }

        // reversed-bin histogram into this row's buffer
#pragma unroll
        for (int j = 0; j < 8; ++j) {
            int bin = (int)av[j];
            bin = bin > NBINS - 1 ? NBINS - 1 : bin;
            atomicAdd(&hist[r][(NBINS - 1) - bin], 1);
        }
        __syncthreads();                   // B1 (the only per-row barrier)

        // ---- all-wave redundant scan: counts + midpoint-weighted sums ----
        // reversed index rb = 8*lane+k  <->  actual bin b = 511-rb, mid = 511.5-rb
        i4 va = *(const i4*)&hist[r][8 * lane];
        i4 vb = *(const i4*)&hist[r][8 * lane + 4];
        const float base = 511.5f - (float)(8 * lane);
        int c0 = va.x;
        int c1 = c0 + va.y;
        int c2 = c1 + va.z;
        int c3 = c2 + va.w;
        int c4 = c3 + vb.x;
        int c5 = c4 + vb.y;
        int c6 = c5 + vb.z;
        int c7 = c6 + vb.w;
        float w0 = (float)va.x * base;
        float w1 = fmaf((float)va.y, base - 1.0f, w0);
        float w2 = fmaf((float)va.z, base - 2.0f, w1);
        float w3 = fmaf((float)va.w, base - 3.0f, w2);
        float w4 = fmaf((float)vb.x, base - 4.0f, w3);
        float w5 = fmaf((float)vb.y, base - 5.0f, w4);
        float w6 = fmaf((float)vb.z, base - 6.0f, w5);
        float w7 = fmaf((float)vb.w, base - 7.0f, w6);

        int   incl  = wave_scan_i(c7);
        int   excl  = incl - c7;           // counts in bins (value-)above this lane's 8
        float winc  = wave_scan_f(w7);
        float wexcl = winc - w7;           // weighted sum of those bins

        float ts = 0.f;
        {
            const int   pre[8]  = {0, c0, c1, c2, c3, c4, c5, c6};
            const int   cum[8]  = {c0, c1, c2, c3, c4, c5, c6, c7};
            const float wpre[8] = {0.f, w0, w1, w2, w3, w4, w5, w6};
#pragma unroll
            for (int k = 0; k < 8; ++k) {
                int s0  = excl + pre[k];
                int e0x = excl + cum[k];
                if (s0 < KSEL && e0x >= KSEL)    // exactly one lane/k fires
                    ts = fmaf((float)(KSEL - s0), base - (float)k,
                              wexcl + wpre[k]);
            }
        }
        ts = wave_bcast63_f(wave_scan_f(ts));   // the single nonzero candidate

        dot = red[r][0][0] + red[r][1][0] + red[r][2][0] + red[r][3][0];
        nrm = red[r][0][1] + red[r][1][1] + red[r][2][1] + red[r][3][1];

        // topk_mean = ts / (64 * KSEL)
        const float topk_mean = ts * (1.0f / (64.0f * KSEL));
        const float cosv = dot * __builtin_amdgcn_rsqf(fmaxf(nrm, 1e-24f));
        const float yt = sigma * topk_mean;
        const float et = __expf(-2.0f * yt);
        const float th = (1.0f - et) * __builtin_amdgcn_rcpf(1.0f + et);  // tanh
        const float gate = __expf(-tau * cosv) * fmaf(w, th, 1.0f);

        f4 oa, ob;
        oa.x = g[0]*gate; oa.y = g[1]*gate; oa.z = g[2]*gate; oa.w = g[3]*gate;
        ob.x = g[4]*gate; ob.y = g[5]*gate; ob.z = g[6]*gate; ob.w = g[7]*gate;
        f4* outr = (f4*)(out + (row0 + r) * D);
        outr[t]      = oa;
        outr[t + NT] = ob;
    }
}

extern "C" void kernel_launch(void* const* d_in, const int* in_sizes, int n_in,
                              void* d_out, int out_size, void* d_ws, size_t ws_size,
                              hipStream_t stream) {
    (void)n_in; (void)out_size; (void)d_ws; (void)ws_size;
    const float* x         = (const float*)d_in[0];
    const float* ema_mean  = (const float*)d_in[1];
    const float* ema_sq    = (const float*)d_in[2];
    const float* ema_out   = (const float*)d_in[3];
    const float* log_tau   = (const float*)d_in[4];
    const float* log_sigma = (const float*)d_in[5];
    const float* log_w     = (const float*)d_in[6];
    float* out = (float*)d_out;

    const int rows = in_sizes[0] / D;   // B*T = 16384
    row_kernel<<<rows / ROWS, NT, 0, stream>>>(x, ema_mean, ema_sq, ema_out,
                                               log_tau, log_sigma, log_w, out);
}

// Round 12
// 45.141 us; speedup vs baseline: 1.0665x; 1.0432x over previous
//
#include <hip/hip_runtime.h>
#include <math.h>

#define D      2048
#define KSEL   256
#define NT     256          // threads per block; NT*8 == D
#define NBINS  512          // bins of width 1/64 over |z| in [0,8)
#define ROWS   2            // rows per block; one hist buffer per row

typedef float f4 __attribute__((ext_vector_type(4)));
typedef int   i4 __attribute__((ext_vector_type(4)));

// tanh-form GELU: x * sigmoid(1.5957691*x + 0.0713548*x^3)
__device__ __forceinline__ float fast_gelu(float x) {
    float x2 = x * x;
    float t  = fmaf(x2, -0.0713548162f, -1.5957691216f);
    float e  = __expf(x * t);
    return x * __builtin_amdgcn_rcpf(1.0f + e);
}

// ---- DPP cross-lane (VALU pipe, no LDS) ----
template<int CTRL, int RMASK>
__device__ __forceinline__ float dpp_mov_f(float v) {
    int r = __builtin_amdgcn_update_dpp(0, __builtin_bit_cast(int, v),
                                        CTRL, RMASK, 0xf, true);
    return __builtin_bit_cast(float, r);
}
template<int CTRL, int RMASK>
__device__ __forceinline__ int dpp_mov_i(int v) {
    return __builtin_amdgcn_update_dpp(0, v, CTRL, RMASK, 0xf, true);
}
// inclusive prefix-sum across 64 lanes; lane 63 ends with the wave total
__device__ __forceinline__ float wave_scan_f(float x) {
    x += dpp_mov_f<0x111, 0xf>(x);   // row_shr:1
    x += dpp_mov_f<0x112, 0xf>(x);   // row_shr:2
    x += dpp_mov_f<0x114, 0xf>(x);   // row_shr:4
    x += dpp_mov_f<0x118, 0xf>(x);   // row_shr:8
    x += dpp_mov_f<0x142, 0xa>(x);   // row_bcast:15 -> rows 1,3
    x += dpp_mov_f<0x143, 0xc>(x);   // row_bcast:31 -> rows 2,3
    return x;
}
__device__ __forceinline__ int wave_scan_i(int x) {
    x += dpp_mov_i<0x111, 0xf>(x);
    x += dpp_mov_i<0x112, 0xf>(x);
    x += dpp_mov_i<0x114, 0xf>(x);
    x += dpp_mov_i<0x118, 0xf>(x);
    x += dpp_mov_i<0x142, 0xa>(x);
    x += dpp_mov_i<0x143, 0xc>(x);
    return x;
}
__device__ __forceinline__ float wave_bcast63_f(float x) {
    int r = __builtin_amdgcn_readlane(__builtin_bit_cast(int, x), 63);
    return __builtin_bit_cast(float, r);
}

// Fused; 2 barriers per row; epilogue entirely in wave0.
__global__ __launch_bounds__(NT) void row_kernel(
    const float* __restrict__ x,
    const float* __restrict__ ema_mean,
    const float* __restrict__ ema_sq,
    const float* __restrict__ ema_out,
    const float* __restrict__ p_log_tau,
    const float* __restrict__ p_log_sigma,
    const float* __restrict__ p_log_w,
    float* __restrict__ out)
{
    __shared__ int   hist[ROWS][NBINS];   // per-row buffer, REVERSED index
    __shared__ float ssred[4];
    __shared__ float red[ROWS][4][2];     // per-row dot/nrm partials
    __shared__ float gate_sh[ROWS];

    const int t    = threadIdx.x;
    const int wave = t >> 6;
    const int lane = t & 63;

    // scalar gate params (uniform; cheap redundant compute per block)
    const float tau   = __expf(p_log_tau[0]);
    const float sigma = __logf(1.0f + __expf(p_log_sigma[0])) + 0.01f;
    const float w     = __logf(1.0f + __expf(p_log_w[0]));

    // ---- inline "prep": per-thread channel constants ----
    f4 m0 = ((const f4*)ema_mean)[t];
    f4 m1 = ((const f4*)ema_mean)[t + NT];
    f4 q0 = ((const f4*)ema_sq)[t];
    f4 q1 = ((const f4*)ema_sq)[t + NT];
    f4 e0 = ((const f4*)ema_out)[t];
    f4 e1 = ((const f4*)ema_out)[t + NT];

    const float mv[8] = {m0.x,m0.y,m0.z,m0.w, m1.x,m1.y,m1.z,m1.w};
    const float qv[8] = {q0.x,q0.y,q0.z,q0.w, q1.x,q1.y,q1.z,q1.w};
    const float ev[8] = {e0.x,e0.y,e0.z,e0.w, e1.x,e1.y,e1.z,e1.w};

    float a_[8], b_[8];
    float ss = 0.f;
#pragma unroll
    for (int j = 0; j < 8; ++j) {
        float v = fmaxf(fmaf(-mv[j], mv[j], qv[j]), 1e-6f);
        a_[j] = 64.0f * __builtin_amdgcn_rsqf(v);     // 64/std
        b_[j] = -mv[j] * a_[j];
        ss = fmaf(ev[j], ev[j], ss);
    }
    ss = wave_scan_f(ss);
    if (lane == 63) ssred[wave] = ss;

    const size_t row0 = (size_t)blockIdx.x * ROWS;
    f4 xa = ((const f4*)(x + row0 * D))[t];
    f4 xb = ((const f4*)(x + row0 * D))[t + NT];

    hist[0][t] = 0;  hist[0][t + NT] = 0;
    hist[1][t] = 0;  hist[1][t + NT] = 0;
    __syncthreads();                       // B0: zeros + ssred visible

    const float inv_nrm =
        1.0f / (sqrtf(ssred[0] + ssred[1] + ssred[2] + ssred[3]) + 1e-8f);
    float u_[8];
#pragma unroll
    for (int j = 0; j < 8; ++j) u_[j] = ev[j] * inv_nrm;

#pragma unroll
    for (int r = 0; r < ROWS; ++r) {
        const float xv[8] = {xa.x,xa.y,xa.z,xa.w, xb.x,xb.y,xb.z,xb.w};

        float g[8], av[8];
        float dot = 0.f, nrm = 0.f;
#pragma unroll
        for (int j = 0; j < 8; ++j) {
            float gg = fast_gelu(xv[j]);
            g[j] = gg;
            av[j] = fabsf(fmaf(xv[j], a_[j], b_[j]));   // 64*|z|
            dot = fmaf(gg, u_[j], dot);
            nrm = fmaf(gg, gg, nrm);
        }

        // prefetch next row's x
        if (r + 1 < ROWS) {
            const float* xn = x + (row0 + r + 1) * D;
            xa = ((const f4*)xn)[t];
            xb = ((const f4*)xn)[t + NT];
        }

        // cross-lane reduce dot/nrm on VALU; overlaps DS atomics below
        dot = wave_scan_f(dot);
        nrm = wave_scan_f(nrm);
        if (lane == 63) { red[r][wave][0] = dot; red[r][wave][1] = nrm; }

        // reversed-bin histogram into this row's buffer
#pragma unroll
        for (int j = 0; j < 8; ++j) {
            int bin = (int)av[j];
            bin = bin > NBINS - 1 ? NBINS - 1 : bin;
            atomicAdd(&hist[r][(NBINS - 1) - bin], 1);
        }
        __syncthreads();                   // B1: hist[r] + red[r] ready

        // ---- wave0 alone: weighted scan -> topk_sum; then the full gate ----
        if (wave == 0) {
            // reversed idx rb = 8*lane+k <-> bin b = 511-rb, midpoint 511.5-rb
            i4 va = *(const i4*)&hist[r][8 * lane];
            i4 vb = *(const i4*)&hist[r][8 * lane + 4];
            const float base = 511.5f - (float)(8 * lane);
            int c0 = va.x;
            int c1 = c0 + va.y;
            int c2 = c1 + va.z;
            int c3 = c2 + va.w;
            int c4 = c3 + vb.x;
            int c5 = c4 + vb.y;
            int c6 = c5 + vb.z;
            int c7 = c6 + vb.w;
            float w0 = (float)va.x * base;
            float w1 = fmaf((float)va.y, base - 1.0f, w0);
            float w2 = fmaf((float)va.z, base - 2.0f, w1);
            float w3 = fmaf((float)va.w, base - 3.0f, w2);
            float w4 = fmaf((float)vb.x, base - 4.0f, w3);
            float w5 = fmaf((float)vb.y, base - 5.0f, w4);
            float w6 = fmaf((float)vb.z, base - 6.0f, w5);
            float w7 = fmaf((float)vb.w, base - 7.0f, w6);

            int   incl  = wave_scan_i(c7);
            int   excl  = incl - c7;       // counts in (value-)higher bins
            float winc  = wave_scan_f(w7);
            float wexcl = winc - w7;       // their midpoint-weighted sum

            float ts = 0.f;
            {
                const int   pre[8]  = {0, c0, c1, c2, c3, c4, c5, c6};
                const int   cum[8]  = {c0, c1, c2, c3, c4, c5, c6, c7};
                const float wpre[8] = {0.f, w0, w1, w2, w3, w4, w5, w6};
#pragma unroll
                for (int k = 0; k < 8; ++k) {
                    int s0  = excl + pre[k];
                    int e0x = excl + cum[k];
                    if (s0 < KSEL && e0x >= KSEL)   // exactly one lane/k fires
                        ts = fmaf((float)(KSEL - s0), base - (float)k,
                                  wexcl + wpre[k]);
                }
            }
            ts = wave_bcast63_f(wave_scan_f(ts));

            float dd = red[r][0][0] + red[r][1][0] + red[r][2][0] + red[r][3][0];
            float nn = red[r][0][1] + red[r][1][1] + red[r][2][1] + red[r][3][1];

            const float topk_mean = ts * (1.0f / (64.0f * KSEL));
            const float cosv = dd * __builtin_amdgcn_rsqf(fmaxf(nn, 1e-24f));
            const float yt = sigma * topk_mean;
            const float et = __expf(-2.0f * yt);
            const float th = (1.0f - et) * __builtin_amdgcn_rcpf(1.0f + et);
            const float gate = __expf(-tau * cosv) * fmaf(w, th, 1.0f);
            if (lane == 0) gate_sh[r] = gate;
        }
        __syncthreads();                   // B2: gate visible

        const float gate = gate_sh[r];
        f4 oa, ob;
        oa.x = g[0]*gate; oa.y = g[1]*gate; oa.z = g[2]*gate; oa.w = g[3]*gate;
        ob.x = g[4]*gate; ob.y = g[5]*gate; ob.z = g[6]*gate; ob.w = g[7]*gate;
        f4* outr = (f4*)(out + (row0 + r) * D);
        outr[t]      = oa;
        outr[t + NT] = ob;
    }
}

extern "C" void kernel_launch(void* const* d_in, const int* in_sizes, int n_in,
                              void* d_out, int out_size, void* d_ws, size_t ws_size,
                              hipStream_t stream) {
    (void)n_in; (void)out_size; (void)d_ws; (void)ws_size;
    const float* x         = (const float*)d_in[0];
    const float* ema_mean  = (const float*)d_in[1];
    const float* ema_sq    = (const float*)d_in[2];
    const float* ema_out   = (const float*)d_in[3];
    const float* log_tau   = (const float*)d_in[4];
    const float* log_sigma = (const float*)d_in[5];
    const float* log_w     = (const float*)d_in[6];
    float* out = (float*)d_out;

    const int rows = in_sizes[0] / D;   // B*T = 16384
    row_kernel<<<rows / ROWS, NT, 0, stream>>>(x, ema_mean, ema_sq, ema_out,
                                               log_tau, log_sigma, log_w, out);
}